// Round 6
// baseline (268.312 us; speedup 1.0000x reference)
//
#include <hip/hip_runtime.h>
#include <hip/hip_bf16.h>

typedef __attribute__((ext_vector_type(8))) short short8;
typedef __attribute__((ext_vector_type(4))) short short4v;
typedef __attribute__((ext_vector_type(4))) float floatx4;

__device__ __forceinline__ unsigned short f2b(float f) {
  unsigned int v;
  __builtin_memcpy(&v, &f, 4);
  unsigned int r = (v + 0x7FFFu + ((v >> 16) & 1u)) >> 16;
  return (unsigned short)r;
}

// pack two fp32 -> bf16x2 (low = a, high = b)
__device__ __forceinline__ unsigned int f2b_pk(float a, float b) {
#if __has_builtin(__builtin_amdgcn_cvt_pk_bf16_f32)
  typedef __attribute__((ext_vector_type(2))) __bf16 bf16x2;
  bf16x2 r = __builtin_amdgcn_cvt_pk_bf16_f32(a, b);
  unsigned int u;
  __builtin_memcpy(&u, &r, 4);
  return u;
#else
  return ((unsigned int)f2b(b) << 16) | (unsigned int)f2b(a);
#endif
}

__device__ __forceinline__ float fast_exp2(float x) {
#if __has_builtin(__builtin_amdgcn_exp2f)
  return __builtin_amdgcn_exp2f(x);
#else
  return __builtin_exp2f(x);
#endif
}

__device__ __forceinline__ void async_copy16(const void* g, void* l) {
  __builtin_amdgcn_global_load_lds(
      (const __attribute__((address_space(1))) unsigned int*)g,
      (__attribute__((address_space(3))) unsigned int*)l, 16, 0, 0);
}

// 0.125 (1/sqrt(dk)) * log2(e): folded into Q so attention uses exp2 directly.
#define QSCALE 0.18033688011112042f

// One launch converts x (1M float4 groups) + 4 weight matrices (256K groups each).
__global__ __launch_bounds__(256) void cvt_all_kernel(
    const float* __restrict__ x,
    const float* __restrict__ w0, const float* __restrict__ w1,
    const float* __restrict__ w2, const float* __restrict__ w3,
    unsigned short* __restrict__ xb,
    unsigned short* __restrict__ d0, unsigned short* __restrict__ d1,
    unsigned short* __restrict__ d2, unsigned short* __restrict__ d3)
{
  int gid = blockIdx.x * 256 + threadIdx.x;
  const float* src;
  unsigned short* dst;
  size_t off;
  if (gid < (1 << 20)) {
    src = x; dst = xb; off = gid;
  } else {
    int g = gid - (1 << 20);
    int w = g >> 18;
    off = g & 0x3FFFF;
    src = (w == 0) ? w0 : (w == 1) ? w1 : (w == 2) ? w2 : w3;
    dst = (w == 0) ? d0 : (w == 1) ? d1 : (w == 2) ? d2 : d3;
  }
  floatx4 v = *(const floatx4*)(src + off * 4);
  unsigned int lo = f2b_pk(v[0], v[1]), hi = f2b_pk(v[2], v[3]);
  unsigned long long r = ((unsigned long long)hi << 32) | lo;
  *(unsigned long long*)(dst + off * 4) = r;
}

// QKV GEMM: C = A @ W^T + bias, 128x128 tile, BK=32. z=0: Q (pre-scaled by
// QSCALE), z=1: K, z=2: V written transposed as VT[bh][d][t].
__global__ __launch_bounds__(256) void gemm_qkv_kernel(
    const unsigned short* __restrict__ A,
    const unsigned short* __restrict__ W0, const unsigned short* __restrict__ W1,
    const unsigned short* __restrict__ W2,
    const float* __restrict__ bias0, const float* __restrict__ bias1,
    const float* __restrict__ bias2,
    unsigned short* __restrict__ Qo, unsigned short* __restrict__ Ko,
    unsigned short* __restrict__ VTo)
{
  const int z = blockIdx.z;
  const unsigned short* W  = (z == 0) ? W0 : (z == 1) ? W1 : W2;
  const float* bias        = (z == 0) ? bias0 : (z == 1) ? bias1 : bias2;

  __shared__ alignas(16) unsigned short sA[128 * 32];
  __shared__ alignas(16) unsigned short sB[128 * 32];

  const int tid  = threadIdx.x;
  const int lane = tid & 63;
  const int wave = tid >> 6;
  const int col  = lane & 15;
  const int quad = lane >> 4;
  const int wm   = (wave >> 1) * 64;
  const int wn   = (wave & 1) * 64;
  const int m0   = blockIdx.y * 128;
  const int n0   = blockIdx.x * 128;

  floatx4 acc[4][4];
#pragma unroll
  for (int i = 0; i < 4; ++i)
#pragma unroll
    for (int j = 0; j < 4; ++j) acc[i][j] = (floatx4){0.f, 0.f, 0.f, 0.f};

  for (int k0 = 0; k0 < 1024; k0 += 32) {
    __syncthreads();
#pragma unroll
    for (int i = 0; i < 2; ++i) {
      int c   = i * 256 + tid;
      int row = c >> 2;
      int ko  = (c & 3) * 8;
      async_copy16(A + (size_t)(m0 + row) * 1024 + k0 + ko, sA + c * 8);
      async_copy16(W + (size_t)(n0 + row) * 1024 + k0 + ko, sB + c * 8);
    }
    __syncthreads();
    short8 af[4], bf[4];
#pragma unroll
    for (int mi = 0; mi < 4; ++mi)
      af[mi] = *(const short8*)(sA + (wm + mi * 16 + col) * 32 + quad * 8);
#pragma unroll
    for (int ni = 0; ni < 4; ++ni)
      bf[ni] = *(const short8*)(sB + (wn + ni * 16 + col) * 32 + quad * 8);
#pragma unroll
    for (int mi = 0; mi < 4; ++mi)
#pragma unroll
      for (int ni = 0; ni < 4; ++ni)
        acc[mi][ni] = __builtin_amdgcn_mfma_f32_16x16x32_bf16(af[mi], bf[ni], acc[mi][ni], 0, 0, 0);
  }

#pragma unroll
  for (int ni = 0; ni < 4; ++ni) {
    int n = n0 + wn + ni * 16 + col;
    float bv = bias[n];
#pragma unroll
    for (int mi = 0; mi < 4; ++mi) {
      int mbase = m0 + wm + mi * 16 + quad * 4;
#pragma unroll
      for (int r = 0; r < 4; ++r) {
        int m = mbase + r;
        float val = acc[mi][ni][r] + bv;
        if (z == 0) {
          Qo[(size_t)m * 1024 + n] = f2b(val * QSCALE);
        } else if (z == 1) {
          Ko[(size_t)m * 1024 + n] = f2b(val);
        } else {
          int d = n & 63, h = n >> 6;
          int bb = m >> 11, t = m & 2047;
          VTo[(((size_t)bb * 16 + h) * 64 + d) * 2048 + t] = f2b(val);
        }
      }
    }
  }
}

// Out-proj GEMM: 128(M)x64(N) tile for occupancy at N=1024; fp32 output.
__global__ __launch_bounds__(256) void gemm_out_kernel(
    const unsigned short* __restrict__ A, const unsigned short* __restrict__ W,
    const float* __restrict__ bias, float* __restrict__ DF)
{
  __shared__ alignas(16) unsigned short sA[128 * 32];
  __shared__ alignas(16) unsigned short sB[64 * 32];

  const int tid  = threadIdx.x;
  const int lane = tid & 63;
  const int wave = tid >> 6;
  const int col  = lane & 15;
  const int quad = lane >> 4;
  const int wm   = (wave >> 1) * 64;
  const int wn   = (wave & 1) * 32;
  const int m0   = blockIdx.y * 128;
  const int n0   = blockIdx.x * 64;

  floatx4 acc[4][2];
#pragma unroll
  for (int i = 0; i < 4; ++i)
#pragma unroll
    for (int j = 0; j < 2; ++j) acc[i][j] = (floatx4){0.f, 0.f, 0.f, 0.f};

  for (int k0 = 0; k0 < 1024; k0 += 32) {
    __syncthreads();
#pragma unroll
    for (int i = 0; i < 2; ++i) {
      int c   = i * 256 + tid;
      int row = c >> 2;
      int ko  = (c & 3) * 8;
      async_copy16(A + (size_t)(m0 + row) * 1024 + k0 + ko, sA + c * 8);
    }
    {
      int row = tid >> 2;
      int ko  = (tid & 3) * 8;
      async_copy16(W + (size_t)(n0 + row) * 1024 + k0 + ko, sB + tid * 8);
    }
    __syncthreads();
    short8 af[4], bf[2];
#pragma unroll
    for (int mi = 0; mi < 4; ++mi)
      af[mi] = *(const short8*)(sA + (wm + mi * 16 + col) * 32 + quad * 8);
#pragma unroll
    for (int ni = 0; ni < 2; ++ni)
      bf[ni] = *(const short8*)(sB + (wn + ni * 16 + col) * 32 + quad * 8);
#pragma unroll
    for (int mi = 0; mi < 4; ++mi)
#pragma unroll
      for (int ni = 0; ni < 2; ++ni)
        acc[mi][ni] = __builtin_amdgcn_mfma_f32_16x16x32_bf16(af[mi], bf[ni], acc[mi][ni], 0, 0, 0);
  }

#pragma unroll
  for (int ni = 0; ni < 2; ++ni) {
    int n = n0 + wn + ni * 16 + col;
    float bv = bias[n];
#pragma unroll
    for (int mi = 0; mi < 4; ++mi) {
      int mbase = m0 + wm + mi * 16 + quad * 4;
#pragma unroll
      for (int r = 0; r < 4; ++r)
        DF[(size_t)(mbase + r) * 1024 + n] = acc[mi][ni][r] + bv;
    }
  }
}

// Flash attention v4: LDS-free K-loop. Block = (bh, 64 q-rows), 4 waves; wave
// w owns k-slice [w*32,+32) of each 128-k tile, accumulating a partial O^T.
// All fragments load DIRECTLY global->VGPR (16 rows x 64B, coalesced), double
// buffered in registers; compiler inserts the vmcnt waits. The k-order inside
// a slice is permuted (sigma(q8+j)=q4+(j>>2)*16+(j&3)) so the exp'd ST^T C-layout
// IS the PV B-fragment in-register (no LDS round-trip, no shuffles); V is
// loaded with the matching sigma (two 8B loads per fragment). LDS only used by
// the 17KB epilogue reduction.
__global__ __launch_bounds__(256, 2) void attention_kernel(
    const unsigned short* __restrict__ Q, const unsigned short* __restrict__ K,
    const unsigned short* __restrict__ VT, unsigned short* __restrict__ CTX)
{
  __shared__ float sO[64 * 64];  // 16 KB (q-major: [q][d])
  __shared__ float sL[4][64];    // 1 KB

  const int bh = blockIdx.x;
  const int b = bh >> 4, h = bh & 15;
  const int q0 = blockIdx.y * 64;
  const int tid  = threadIdx.x;
  const int lane = tid & 63;
  const int wave = tid >> 6;
  const int col  = lane & 15;
  const int quad = lane >> 4;

  const unsigned short* Kg  = K + ((size_t)b * 2048) * 1024 + h * 64;
  const unsigned short* VTg = VT + (size_t)bh * 64 * 2048;

  // Q fragments (B-operand layout), loaded once directly from global.
  short8 qf[4][2];
#pragma unroll
  for (int qc = 0; qc < 4; ++qc)
#pragma unroll
    for (int s = 0; s < 2; ++s)
      qf[qc][s] = *(const short8*)(Q + (size_t)(b * 2048 + q0 + qc * 16 + col) * 1024
                                    + h * 64 + s * 32 + quad * 8);

  floatx4 Oacc[4][4];  // [nd][qc], O^T partial: d=nd*16+quad*4+r, q=qc*16+col
#pragma unroll
  for (int nd = 0; nd < 4; ++nd)
#pragma unroll
    for (int qc = 0; qc < 4; ++qc) Oacc[nd][qc] = (floatx4){0.f, 0.f, 0.f, 0.f};
  float lacc[4] = {0.f, 0.f, 0.f, 0.f};

  short8  kfb[2][2][2];   // [buf][kr][s]: K[kt+w*32+kr*16+col][s*32+quad*8+j]
  short4v vfb[2][4][2];   // [buf][nd][half]: VT[nd*16+col][kt+w*32+half*16+quad*4+jj]

  const int ksl = wave * 32;

#define LOAD_K(buf, kt)                                                        \
  {                                                                            \
    _Pragma("unroll") for (int kr = 0; kr < 2; ++kr)                           \
      _Pragma("unroll") for (int s = 0; s < 2; ++s)                            \
        kfb[buf][kr][s] = *(const short8*)(                                    \
            Kg + (size_t)((kt) + ksl + kr * 16 + col) * 1024 + s * 32 + quad * 8); \
  }
#define LOAD_V(buf, kt)                                                        \
  {                                                                            \
    _Pragma("unroll") for (int nd = 0; nd < 4; ++nd)                           \
      _Pragma("unroll") for (int hf = 0; hf < 2; ++hf)                         \
        vfb[buf][nd][hf] = *(const short4v*)(                                  \
            VTg + (size_t)(nd * 16 + col) * 2048 + (kt) + ksl + hf * 16 + quad * 4); \
  }

  LOAD_K(0, 0)
  LOAD_V(0, 0)

#pragma unroll 2
  for (int t = 0; t < 16; ++t) {
    const int cur = t & 1, nxt = cur ^ 1;
    if (t < 15) {
      LOAD_K(nxt, (t + 1) * 128)
      LOAD_V(nxt, (t + 1) * 128)
    }

    // QK^T (swapped): ST[kr][qc] = D[m=k_local][n=q]
    floatx4 ST[2][4];
#pragma unroll
    for (int kr = 0; kr < 2; ++kr)
#pragma unroll
      for (int qc = 0; qc < 4; ++qc) {
        ST[kr][qc] = (floatx4){0.f, 0.f, 0.f, 0.f};
        ST[kr][qc] = __builtin_amdgcn_mfma_f32_16x16x32_bf16(
            kfb[cur][kr][0], qf[qc][0], ST[kr][qc], 0, 0, 0);
        ST[kr][qc] = __builtin_amdgcn_mfma_f32_16x16x32_bf16(
            kfb[cur][kr][1], qf[qc][1], ST[kr][qc], 0, 0, 0);
      }

    // exp2 -> P fragment (B-operand under sigma ordering), all in-register.
    short8 pf[4];
#pragma unroll
    for (int qc = 0; qc < 4; ++qc) {
      float p00 = fast_exp2(ST[0][qc][0]);
      float p01 = fast_exp2(ST[0][qc][1]);
      float p02 = fast_exp2(ST[0][qc][2]);
      float p03 = fast_exp2(ST[0][qc][3]);
      float p10 = fast_exp2(ST[1][qc][0]);
      float p11 = fast_exp2(ST[1][qc][1]);
      float p12 = fast_exp2(ST[1][qc][2]);
      float p13 = fast_exp2(ST[1][qc][3]);
      lacc[qc] += ((p00 + p01) + (p02 + p03)) + ((p10 + p11) + (p12 + p13));
      alignas(16) unsigned int d4[4] = {
          f2b_pk(p00, p01), f2b_pk(p02, p03), f2b_pk(p10, p11), f2b_pk(p12, p13)};
      __builtin_memcpy(&pf[qc], d4, 16);
    }

    // PV (swapped): Oacc[nd][qc] += mfma(A=vf, B=pf)
#pragma unroll
    for (int nd = 0; nd < 4; ++nd) {
      short8 vf = __builtin_shufflevector(vfb[cur][nd][0], vfb[cur][nd][1],
                                          0, 1, 2, 3, 4, 5, 6, 7);
#pragma unroll
      for (int qc = 0; qc < 4; ++qc)
        Oacc[nd][qc] = __builtin_amdgcn_mfma_f32_16x16x32_bf16(
            vf, pf[qc], Oacc[nd][qc], 0, 0, 0);
    }
  }
#undef LOAD_K
#undef LOAD_V

  // ---- epilogue ----
#pragma unroll
  for (int qc = 0; qc < 4; ++qc) {
    lacc[qc] += __shfl_xor(lacc[qc], 16, 64);
    lacc[qc] += __shfl_xor(lacc[qc], 32, 64);
  }
  if (quad == 0) {
#pragma unroll
    for (int qc = 0; qc < 4; ++qc) sL[wave][qc * 16 + col] = lacc[qc];
  }

#pragma unroll 1
  for (int ww = 0; ww < 4; ++ww) {
    __syncthreads();
    if (wave == ww) {
#pragma unroll
      for (int nd = 0; nd < 4; ++nd)
#pragma unroll
        for (int qc = 0; qc < 4; ++qc)
#pragma unroll
          for (int r = 0; r < 4; ++r) {
            int idx = (qc * 16 + col) * 64 + nd * 16 + quad * 4 + r;
            if (ww == 0) sO[idx] = Oacc[nd][qc][r];
            else         sO[idx] += Oacc[nd][qc][r];
          }
    }
  }
  __syncthreads();

  {
    int q = tid >> 2, c = tid & 3;
    float l = sL[0][q] + sL[1][q] + sL[2][q] + sL[3][q];
    float inv = 1.f / l;
    const float* row = sO + q * 64 + c * 16;
    unsigned short* dst = CTX + (size_t)(b * 2048 + q0 + q) * 1024 + h * 64 + c * 16;
#pragma unroll
    for (int hf = 0; hf < 2; ++hf) {
      alignas(16) unsigned short ob[8];
#pragma unroll
      for (int j = 0; j < 8; ++j) ob[j] = f2b(row[hf * 8 + j] * inv);
      *(short8*)(dst + hf * 8) = *(const short8*)ob;
    }
  }
}

extern "C" void kernel_launch(void* const* d_in, const int* in_sizes, int n_in,
                              void* d_out, int out_size, void* d_ws, size_t ws_size,
                              hipStream_t stream) {
  const float* x   = (const float*)d_in[0];
  const float* W_q = (const float*)d_in[1];
  const float* b_q = (const float*)d_in[2];
  const float* W_k = (const float*)d_in[3];
  const float* b_k = (const float*)d_in[4];
  const float* W_v = (const float*)d_in[5];
  const float* b_v = (const float*)d_in[6];
  const float* W_o = (const float*)d_in[7];
  const float* b_o = (const float*)d_in[8];
  float* out = (float*)d_out;

  const size_t NX = (size_t)4096 * 1024;
  const size_t NW = (size_t)1024 * 1024;

  unsigned short* p   = (unsigned short*)d_ws;
  unsigned short* xb  = p;  p += NX;
  unsigned short* Wqb = p;  p += NW;
  unsigned short* Wkb = p;  p += NW;
  unsigned short* Wvb = p;  p += NW;
  unsigned short* Wob = p;  p += NW;
  unsigned short* Q   = p;  p += NX;
  unsigned short* Kb  = p;  p += NX;
  unsigned short* VT  = p;  p += NX;  // [32][64][2048]
  unsigned short* CTX = p;  p += NX;

  dim3 blk(256);
  cvt_all_kernel<<<dim3(8192), blk, 0, stream>>>(
      x, W_q, W_k, W_v, W_o, xb, Wqb, Wkb, Wvb, Wob);
  gemm_qkv_kernel<<<dim3(8, 32, 3), blk, 0, stream>>>(
      xb, Wqb, Wkb, Wvb, b_q, b_k, b_v, Q, Kb, VT);
  attention_kernel<<<dim3(32, 32), blk, 0, stream>>>(Q, Kb, VT, CTX);
  gemm_out_kernel<<<dim3(16, 32), blk, 0, stream>>>(CTX, Wob, b_o, out);
}

// Round 7
// 220.966 us; speedup vs baseline: 1.2143x; 1.2143x over previous
//
#include <hip/hip_runtime.h>
#include <hip/hip_bf16.h>

typedef __attribute__((ext_vector_type(8))) short short8;
typedef __attribute__((ext_vector_type(4))) short short4v;
typedef __attribute__((ext_vector_type(4))) float floatx4;

__device__ __forceinline__ unsigned short f2b(float f) {
  unsigned int v;
  __builtin_memcpy(&v, &f, 4);
  unsigned int r = (v + 0x7FFFu + ((v >> 16) & 1u)) >> 16;
  return (unsigned short)r;
}

// pack two fp32 -> bf16x2 (low = a, high = b)
__device__ __forceinline__ unsigned int f2b_pk(float a, float b) {
#if __has_builtin(__builtin_amdgcn_cvt_pk_bf16_f32)
  typedef __attribute__((ext_vector_type(2))) __bf16 bf16x2;
  bf16x2 r = __builtin_amdgcn_cvt_pk_bf16_f32(a, b);
  unsigned int u;
  __builtin_memcpy(&u, &r, 4);
  return u;
#else
  return ((unsigned int)f2b(b) << 16) | (unsigned int)f2b(a);
#endif
}

__device__ __forceinline__ float fast_exp2(float x) {
#if __has_builtin(__builtin_amdgcn_exp2f)
  return __builtin_amdgcn_exp2f(x);
#else
  return __builtin_exp2f(x);
#endif
}

__device__ __forceinline__ void async_copy16(const void* g, void* l) {
  __builtin_amdgcn_global_load_lds(
      (const __attribute__((address_space(1))) unsigned int*)g,
      (__attribute__((address_space(3))) unsigned int*)l, 16, 0, 0);
}

// 0.125 (1/sqrt(dk)) * log2(e): folded into Q so attention uses exp2 directly.
#define QSCALE 0.18033688011112042f

// One launch converts x (1M float4 groups) + 4 weight matrices (256K groups each).
__global__ __launch_bounds__(256) void cvt_all_kernel(
    const float* __restrict__ x,
    const float* __restrict__ w0, const float* __restrict__ w1,
    const float* __restrict__ w2, const float* __restrict__ w3,
    unsigned short* __restrict__ xb,
    unsigned short* __restrict__ d0, unsigned short* __restrict__ d1,
    unsigned short* __restrict__ d2, unsigned short* __restrict__ d3)
{
  int gid = blockIdx.x * 256 + threadIdx.x;
  const float* src;
  unsigned short* dst;
  size_t off;
  if (gid < (1 << 20)) {
    src = x; dst = xb; off = gid;
  } else {
    int g = gid - (1 << 20);
    int w = g >> 18;
    off = g & 0x3FFFF;
    src = (w == 0) ? w0 : (w == 1) ? w1 : (w == 2) ? w2 : w3;
    dst = (w == 0) ? d0 : (w == 1) ? d1 : (w == 2) ? d2 : d3;
  }
  floatx4 v = *(const floatx4*)(src + off * 4);
  unsigned int lo = f2b_pk(v[0], v[1]), hi = f2b_pk(v[2], v[3]);
  unsigned long long r = ((unsigned long long)hi << 32) | lo;
  *(unsigned long long*)(dst + off * 4) = r;
}

// QKV GEMM: C = A @ W^T + bias, 128x128 tile, BK=64 (two 32-k slabs so each
// slab keeps the conflict-free 64B-row layout AND global_load_lds dest stays
// wave-linear). z=0: Q (pre-scaled), z=1: K, z=2: V written as VT[bh][d][t].
__global__ __launch_bounds__(256) void gemm_qkv_kernel(
    const unsigned short* __restrict__ A,
    const unsigned short* __restrict__ W0, const unsigned short* __restrict__ W1,
    const unsigned short* __restrict__ W2,
    const float* __restrict__ bias0, const float* __restrict__ bias1,
    const float* __restrict__ bias2,
    unsigned short* __restrict__ Qo, unsigned short* __restrict__ Ko,
    unsigned short* __restrict__ VTo)
{
  const int z = blockIdx.z;
  const unsigned short* W  = (z == 0) ? W0 : (z == 1) ? W1 : W2;
  const float* bias        = (z == 0) ? bias0 : (z == 1) ? bias1 : bias2;

  __shared__ alignas(16) unsigned short sA[2 * 128 * 32];  // [slab][row][32]
  __shared__ alignas(16) unsigned short sB[2 * 128 * 32];

  const int tid  = threadIdx.x;
  const int lane = tid & 63;
  const int wave = tid >> 6;
  const int col  = lane & 15;
  const int quad = lane >> 4;
  const int wm   = (wave >> 1) * 64;
  const int wn   = (wave & 1) * 64;
  const int m0   = blockIdx.y * 128;
  const int n0   = blockIdx.x * 128;

  floatx4 acc[4][4];
#pragma unroll
  for (int i = 0; i < 4; ++i)
#pragma unroll
    for (int j = 0; j < 4; ++j) acc[i][j] = (floatx4){0.f, 0.f, 0.f, 0.f};

  for (int k0 = 0; k0 < 1024; k0 += 64) {
    __syncthreads();
#pragma unroll
    for (int i = 0; i < 4; ++i) {
      int c    = i * 256 + tid;
      int slab = c >> 9;
      int cc   = c & 511;
      int row  = cc >> 2;
      int ko   = (cc & 3) * 8;
      int kg   = k0 + slab * 32 + ko;
      async_copy16(A + (size_t)(m0 + row) * 1024 + kg, sA + c * 8);
      async_copy16(W + (size_t)(n0 + row) * 1024 + kg, sB + c * 8);
    }
    __syncthreads();
#pragma unroll
    for (int ks = 0; ks < 2; ++ks) {
      short8 af[4], bf[4];
#pragma unroll
      for (int mi = 0; mi < 4; ++mi)
        af[mi] = *(const short8*)(sA + ks * 4096 + (wm + mi * 16 + col) * 32 + quad * 8);
#pragma unroll
      for (int ni = 0; ni < 4; ++ni)
        bf[ni] = *(const short8*)(sB + ks * 4096 + (wn + ni * 16 + col) * 32 + quad * 8);
#pragma unroll
      for (int mi = 0; mi < 4; ++mi)
#pragma unroll
        for (int ni = 0; ni < 4; ++ni)
          acc[mi][ni] = __builtin_amdgcn_mfma_f32_16x16x32_bf16(af[mi], bf[ni], acc[mi][ni], 0, 0, 0);
    }
  }

#pragma unroll
  for (int ni = 0; ni < 4; ++ni) {
    int n = n0 + wn + ni * 16 + col;
    float bv = bias[n];
#pragma unroll
    for (int mi = 0; mi < 4; ++mi) {
      int mbase = m0 + wm + mi * 16 + quad * 4;
#pragma unroll
      for (int r = 0; r < 4; ++r) {
        int m = mbase + r;
        float val = acc[mi][ni][r] + bv;
        if (z == 0) {
          Qo[(size_t)m * 1024 + n] = f2b(val * QSCALE);
        } else if (z == 1) {
          Ko[(size_t)m * 1024 + n] = f2b(val);
        } else {
          int d = n & 63, h = n >> 6;
          int bb = m >> 11, t = m & 2047;
          VTo[(((size_t)bb * 16 + h) * 64 + d) * 2048 + t] = f2b(val);
        }
      }
    }
  }
}

// Out-proj GEMM: 128(M)x64(N) tile, BK=64 two-slab; fp32 output.
__global__ __launch_bounds__(256) void gemm_out_kernel(
    const unsigned short* __restrict__ A, const unsigned short* __restrict__ W,
    const float* __restrict__ bias, float* __restrict__ DF)
{
  __shared__ alignas(16) unsigned short sA[2 * 128 * 32];
  __shared__ alignas(16) unsigned short sB[2 * 64 * 32];

  const int tid  = threadIdx.x;
  const int lane = tid & 63;
  const int wave = tid >> 6;
  const int col  = lane & 15;
  const int quad = lane >> 4;
  const int wm   = (wave >> 1) * 64;
  const int wn   = (wave & 1) * 32;
  const int m0   = blockIdx.y * 128;
  const int n0   = blockIdx.x * 64;

  floatx4 acc[4][2];
#pragma unroll
  for (int i = 0; i < 4; ++i)
#pragma unroll
    for (int j = 0; j < 2; ++j) acc[i][j] = (floatx4){0.f, 0.f, 0.f, 0.f};

  for (int k0 = 0; k0 < 1024; k0 += 64) {
    __syncthreads();
#pragma unroll
    for (int i = 0; i < 4; ++i) {
      int c    = i * 256 + tid;
      int slab = c >> 9;
      int cc   = c & 511;
      int row  = cc >> 2;
      int ko   = (cc & 3) * 8;
      async_copy16(A + (size_t)(m0 + row) * 1024 + k0 + slab * 32 + ko, sA + c * 8);
    }
#pragma unroll
    for (int i = 0; i < 2; ++i) {
      int c    = i * 256 + tid;
      int slab = c >> 8;
      int cc   = c & 255;
      int row  = cc >> 2;
      int ko   = (cc & 3) * 8;
      async_copy16(W + (size_t)(n0 + row) * 1024 + k0 + slab * 32 + ko, sB + c * 8);
    }
    __syncthreads();
#pragma unroll
    for (int ks = 0; ks < 2; ++ks) {
      short8 af[4], bf[2];
#pragma unroll
      for (int mi = 0; mi < 4; ++mi)
        af[mi] = *(const short8*)(sA + ks * 4096 + (wm + mi * 16 + col) * 32 + quad * 8);
#pragma unroll
      for (int ni = 0; ni < 2; ++ni)
        bf[ni] = *(const short8*)(sB + ks * 2048 + (wn + ni * 16 + col) * 32 + quad * 8);
#pragma unroll
      for (int mi = 0; mi < 4; ++mi)
#pragma unroll
        for (int ni = 0; ni < 2; ++ni)
          acc[mi][ni] = __builtin_amdgcn_mfma_f32_16x16x32_bf16(af[mi], bf[ni], acc[mi][ni], 0, 0, 0);
    }
  }

#pragma unroll
  for (int ni = 0; ni < 2; ++ni) {
    int n = n0 + wn + ni * 16 + col;
    float bv = bias[n];
#pragma unroll
    for (int mi = 0; mi < 4; ++mi) {
      int mbase = m0 + wm + mi * 16 + quad * 4;
#pragma unroll
      for (int r = 0; r < 4; ++r)
        DF[(size_t)(mbase + r) * 1024 + n] = acc[mi][ni][r] + bv;
    }
  }
}

// Flash attention (R4 structure, 77us known-good): max-free softmax, Q
// pre-scaled so p=exp2(s). QK computed transposed (A=K,B=Q) so each lane
// holds 4 consecutive k for fixed q=col -> packed b64 P-writes, b128 P-reads,
// scalar per-lane row sum. sP wave-private (no barrier on P round-trip).
__global__ __launch_bounds__(256, 4) void attention_kernel(
    const unsigned short* __restrict__ Q, const unsigned short* __restrict__ K,
    const unsigned short* __restrict__ VT, unsigned short* __restrict__ CTX)
{
  __shared__ alignas(16) unsigned short sQ[2 * 64 * 32];
  __shared__ alignas(16) unsigned short sK[2 * 64 * 32];
  __shared__ alignas(16) unsigned short sV[2 * 64 * 32];
  __shared__ alignas(16) unsigned short sP[4][16 * 72];  // [wave][q=16 rows x 72]

  const int bh = blockIdx.x;
  const int b = bh >> 4, h = bh & 15;
  const int q0 = blockIdx.y * 64;
  const int tid  = threadIdx.x;
  const int lane = tid & 63;
  const int wave = tid >> 6;
  const int col  = lane & 15;
  const int quad = lane >> 4;

#pragma unroll
  for (int i = 0; i < 2; ++i) {
    int r = tid >> 2;
    int ko = (tid & 3) * 8;
    async_copy16(Q + (size_t)(b * 2048 + q0 + r) * 1024 + h * 64 + i * 32 + ko,
                 sQ + (i * 256 + tid) * 8);
  }
  __syncthreads();
  short8 qf[2];
  qf[0] = *(const short8*)(sQ + (wave * 16 + col) * 32 + quad * 8);
  qf[1] = *(const short8*)(sQ + 2048 + (wave * 16 + col) * 32 + quad * 8);

  floatx4 Oacc[4];
#pragma unroll
  for (int f = 0; f < 4; ++f) Oacc[f] = (floatx4){0.f, 0.f, 0.f, 0.f};
  float lacc = 0.f;  // per-lane partial sum for q = col

  unsigned short* myP = &sP[wave][0];

  for (int kt = 0; kt < 2048; kt += 64) {
    __syncthreads();
#pragma unroll
    for (int i = 0; i < 2; ++i) {
      int r = tid >> 2;
      int ko = (tid & 3) * 8;
      async_copy16(K + (size_t)(b * 2048 + kt + r) * 1024 + h * 64 + i * 32 + ko,
                   sK + (i * 256 + tid) * 8);
      async_copy16(VT + ((size_t)bh * 64 + r) * 2048 + kt + i * 32 + ko,
                   sV + (i * 256 + tid) * 8);
    }
    __syncthreads();

    // S^T blocks: rows k = f*16+quad*4+r, col q
    floatx4 ST[4];
#pragma unroll
    for (int f = 0; f < 4; ++f) {
      ST[f] = (floatx4){0.f, 0.f, 0.f, 0.f};
      short8 kf0 = *(const short8*)(sK + (f * 16 + col) * 32 + quad * 8);
      ST[f] = __builtin_amdgcn_mfma_f32_16x16x32_bf16(kf0, qf[0], ST[f], 0, 0, 0);
      short8 kf1 = *(const short8*)(sK + 2048 + (f * 16 + col) * 32 + quad * 8);
      ST[f] = __builtin_amdgcn_mfma_f32_16x16x32_bf16(kf1, qf[1], ST[f], 0, 0, 0);
    }

#pragma unroll
    for (int f = 0; f < 4; ++f) {
      float p0 = fast_exp2(ST[f][0]);
      float p1 = fast_exp2(ST[f][1]);
      float p2 = fast_exp2(ST[f][2]);
      float p3 = fast_exp2(ST[f][3]);
      lacc += (p0 + p1) + (p2 + p3);
      unsigned long long w =
          ((unsigned long long)f2b_pk(p2, p3) << 32) | f2b_pk(p0, p1);
      *(unsigned long long*)(myP + col * 72 + f * 16 + quad * 4) = w;
    }

    // wave-private sP: lgkmcnt orders write->read, no barrier needed.
    short8 pf0 = *(const short8*)(myP + col * 72 + quad * 8);
    short8 pf1 = *(const short8*)(myP + col * 72 + 32 + quad * 8);
#pragma unroll
    for (int f = 0; f < 4; ++f) {
      short8 vf0 = *(const short8*)(sV + (f * 16 + col) * 32 + quad * 8);
      Oacc[f] = __builtin_amdgcn_mfma_f32_16x16x32_bf16(pf0, vf0, Oacc[f], 0, 0, 0);
      short8 vf1 = *(const short8*)(sV + 2048 + (f * 16 + col) * 32 + quad * 8);
      Oacc[f] = __builtin_amdgcn_mfma_f32_16x16x32_bf16(pf1, vf1, Oacc[f], 0, 0, 0);
    }
  }

  // lacc holds partial sum for q=col over this quad's k slices; sum quads.
  lacc += __shfl_xor(lacc, 16, 64);
  lacc += __shfl_xor(lacc, 32, 64);
  // row sums for this lane's output rows q = quad*4+r
  float inv[4];
#pragma unroll
  for (int r = 0; r < 4; ++r) inv[r] = 1.f / __shfl(lacc, quad * 4 + r, 16);

#pragma unroll
  for (int f = 0; f < 4; ++f) {
#pragma unroll
    for (int r = 0; r < 4; ++r) {
      int q = q0 + wave * 16 + quad * 4 + r;
      int d = f * 16 + col;
      CTX[(size_t)(b * 2048 + q) * 1024 + h * 64 + d] = f2b(Oacc[f][r] * inv[r]);
    }
  }
}

extern "C" void kernel_launch(void* const* d_in, const int* in_sizes, int n_in,
                              void* d_out, int out_size, void* d_ws, size_t ws_size,
                              hipStream_t stream) {
  const float* x   = (const float*)d_in[0];
  const float* W_q = (const float*)d_in[1];
  const float* b_q = (const float*)d_in[2];
  const float* W_k = (const float*)d_in[3];
  const float* b_k = (const float*)d_in[4];
  const float* W_v = (const float*)d_in[5];
  const float* b_v = (const float*)d_in[6];
  const float* W_o = (const float*)d_in[7];
  const float* b_o = (const float*)d_in[8];
  float* out = (float*)d_out;

  const size_t NX = (size_t)4096 * 1024;
  const size_t NW = (size_t)1024 * 1024;

  unsigned short* p   = (unsigned short*)d_ws;
  unsigned short* xb  = p;  p += NX;
  unsigned short* Wqb = p;  p += NW;
  unsigned short* Wkb = p;  p += NW;
  unsigned short* Wvb = p;  p += NW;
  unsigned short* Wob = p;  p += NW;
  unsigned short* Q   = p;  p += NX;
  unsigned short* Kb  = p;  p += NX;
  unsigned short* VT  = p;  p += NX;  // [32][64][2048]
  unsigned short* CTX = p;  p += NX;

  dim3 blk(256);
  cvt_all_kernel<<<dim3(8192), blk, 0, stream>>>(
      x, W_q, W_k, W_v, W_o, xb, Wqb, Wkb, Wvb, Wob);
  gemm_qkv_kernel<<<dim3(8, 32, 3), blk, 0, stream>>>(
      xb, Wqb, Wkb, Wvb, b_q, b_k, b_v, Q, Kb, VT);
  attention_kernel<<<dim3(32, 32), blk, 0, stream>>>(Q, Kb, VT, CTX);
  gemm_out_kernel<<<dim3(16, 32), blk, 0, stream>>>(CTX, Wob, b_o, out);
}

// Round 8
// 202.116 us; speedup vs baseline: 1.3275x; 1.0933x over previous
//
#include <hip/hip_runtime.h>
#include <hip/hip_bf16.h>

typedef __attribute__((ext_vector_type(8))) short short8;
typedef __attribute__((ext_vector_type(4))) short short4v;
typedef __attribute__((ext_vector_type(4))) float floatx4;

__device__ __forceinline__ unsigned short f2b(float f) {
  unsigned int v;
  __builtin_memcpy(&v, &f, 4);
  unsigned int r = (v + 0x7FFFu + ((v >> 16) & 1u)) >> 16;
  return (unsigned short)r;
}

// pack two fp32 -> bf16x2 (low = a, high = b)
__device__ __forceinline__ unsigned int f2b_pk(float a, float b) {
#if __has_builtin(__builtin_amdgcn_cvt_pk_bf16_f32)
  typedef __attribute__((ext_vector_type(2))) __bf16 bf16x2;
  bf16x2 r = __builtin_amdgcn_cvt_pk_bf16_f32(a, b);
  unsigned int u;
  __builtin_memcpy(&u, &r, 4);
  return u;
#else
  return ((unsigned int)f2b(b) << 16) | (unsigned int)f2b(a);
#endif
}

__device__ __forceinline__ float fast_exp2(float x) {
#if __has_builtin(__builtin_amdgcn_exp2f)
  return __builtin_amdgcn_exp2f(x);
#else
  return __builtin_exp2f(x);
#endif
}

__device__ __forceinline__ void async_copy16(const void* g, void* l) {
  __builtin_amdgcn_global_load_lds(
      (const __attribute__((address_space(1))) unsigned int*)g,
      (__attribute__((address_space(3))) unsigned int*)l, 16, 0, 0);
}

// 0.125 (1/sqrt(dk)) * log2(e): folded into Q so attention uses exp2 directly.
#define QSCALE 0.18033688011112042f

// XOR bank swizzle for [rows][32-short] LDS tiles staged by global_load_lds:
// row r's 16B chunk c lives in slot c ^ ((r>>1)&3). Staging picks the global
// chunk per slot; frag reads use quad ^ ((col>>1)&3) (read row-bases are
// multiples of 16, so the row term vanishes mod 4). 8-way -> 2-way (free).

// One launch converts x (1M float4 groups) + 4 weight matrices (256K groups each).
__global__ __launch_bounds__(256) void cvt_all_kernel(
    const float* __restrict__ x,
    const float* __restrict__ w0, const float* __restrict__ w1,
    const float* __restrict__ w2, const float* __restrict__ w3,
    unsigned short* __restrict__ xb,
    unsigned short* __restrict__ d0, unsigned short* __restrict__ d1,
    unsigned short* __restrict__ d2, unsigned short* __restrict__ d3)
{
  int gid = blockIdx.x * 256 + threadIdx.x;
  const float* src;
  unsigned short* dst;
  size_t off;
  if (gid < (1 << 20)) {
    src = x; dst = xb; off = gid;
  } else {
    int g = gid - (1 << 20);
    int w = g >> 18;
    off = g & 0x3FFFF;
    src = (w == 0) ? w0 : (w == 1) ? w1 : (w == 2) ? w2 : w3;
    dst = (w == 0) ? d0 : (w == 1) ? d1 : (w == 2) ? d2 : d3;
  }
  floatx4 v = *(const floatx4*)(src + off * 4);
  unsigned int lo = f2b_pk(v[0], v[1]), hi = f2b_pk(v[2], v[3]);
  unsigned long long r = ((unsigned long long)hi << 32) | lo;
  *(unsigned long long*)(dst + off * 4) = r;
}

// QKV GEMM: C = A @ W^T + bias, 128x128 tile, BK=32 (R4 structure + swizzle).
// z=0: Q (pre-scaled by QSCALE), z=1: K, z=2: V written as VT[bh][d][t].
__global__ __launch_bounds__(256) void gemm_qkv_kernel(
    const unsigned short* __restrict__ A,
    const unsigned short* __restrict__ W0, const unsigned short* __restrict__ W1,
    const unsigned short* __restrict__ W2,
    const float* __restrict__ bias0, const float* __restrict__ bias1,
    const float* __restrict__ bias2,
    unsigned short* __restrict__ Qo, unsigned short* __restrict__ Ko,
    unsigned short* __restrict__ VTo)
{
  const int z = blockIdx.z;
  const unsigned short* W  = (z == 0) ? W0 : (z == 1) ? W1 : W2;
  const float* bias        = (z == 0) ? bias0 : (z == 1) ? bias1 : bias2;

  __shared__ alignas(16) unsigned short sA[128 * 32];
  __shared__ alignas(16) unsigned short sB[128 * 32];

  const int tid  = threadIdx.x;
  const int lane = tid & 63;
  const int wave = tid >> 6;
  const int col  = lane & 15;
  const int quad = lane >> 4;
  const int wm   = (wave >> 1) * 64;
  const int wn   = (wave & 1) * 64;
  const int m0   = blockIdx.y * 128;
  const int n0   = blockIdx.x * 128;
  const int swz8 = (quad ^ ((col >> 1) & 3)) * 8;

  floatx4 acc[4][4];
#pragma unroll
  for (int i = 0; i < 4; ++i)
#pragma unroll
    for (int j = 0; j < 4; ++j) acc[i][j] = (floatx4){0.f, 0.f, 0.f, 0.f};

  for (int k0 = 0; k0 < 1024; k0 += 32) {
    __syncthreads();
#pragma unroll
    for (int i = 0; i < 2; ++i) {
      int c   = i * 256 + tid;
      int row = c >> 2;
      int cs  = (c & 3) ^ ((c >> 3) & 3);  // swizzled source chunk
      int ko  = cs * 8;
      async_copy16(A + (size_t)(m0 + row) * 1024 + k0 + ko, sA + c * 8);
      async_copy16(W + (size_t)(n0 + row) * 1024 + k0 + ko, sB + c * 8);
    }
    __syncthreads();
    short8 af[4], bf[4];
#pragma unroll
    for (int mi = 0; mi < 4; ++mi)
      af[mi] = *(const short8*)(sA + (wm + mi * 16 + col) * 32 + swz8);
#pragma unroll
    for (int ni = 0; ni < 4; ++ni)
      bf[ni] = *(const short8*)(sB + (wn + ni * 16 + col) * 32 + swz8);
#pragma unroll
    for (int mi = 0; mi < 4; ++mi)
#pragma unroll
      for (int ni = 0; ni < 4; ++ni)
        acc[mi][ni] = __builtin_amdgcn_mfma_f32_16x16x32_bf16(af[mi], bf[ni], acc[mi][ni], 0, 0, 0);
  }

#pragma unroll
  for (int ni = 0; ni < 4; ++ni) {
    int n = n0 + wn + ni * 16 + col;
    float bv = bias[n];
#pragma unroll
    for (int mi = 0; mi < 4; ++mi) {
      int mbase = m0 + wm + mi * 16 + quad * 4;
#pragma unroll
      for (int r = 0; r < 4; ++r) {
        int m = mbase + r;
        float val = acc[mi][ni][r] + bv;
        if (z == 0) {
          Qo[(size_t)m * 1024 + n] = f2b(val * QSCALE);
        } else if (z == 1) {
          Ko[(size_t)m * 1024 + n] = f2b(val);
        } else {
          int d = n & 63, h = n >> 6;
          int bb = m >> 11, t = m & 2047;
          VTo[(((size_t)bb * 16 + h) * 64 + d) * 2048 + t] = f2b(val);
        }
      }
    }
  }
}

// Out-proj GEMM: 128(M)x64(N) tile, BK=32 + swizzle; fp32 output.
__global__ __launch_bounds__(256) void gemm_out_kernel(
    const unsigned short* __restrict__ A, const unsigned short* __restrict__ W,
    const float* __restrict__ bias, float* __restrict__ DF)
{
  __shared__ alignas(16) unsigned short sA[128 * 32];
  __shared__ alignas(16) unsigned short sB[64 * 32];

  const int tid  = threadIdx.x;
  const int lane = tid & 63;
  const int wave = tid >> 6;
  const int col  = lane & 15;
  const int quad = lane >> 4;
  const int wm   = (wave >> 1) * 64;
  const int wn   = (wave & 1) * 32;
  const int m0   = blockIdx.y * 128;
  const int n0   = blockIdx.x * 64;
  const int swz8 = (quad ^ ((col >> 1) & 3)) * 8;

  floatx4 acc[4][2];
#pragma unroll
  for (int i = 0; i < 4; ++i)
#pragma unroll
    for (int j = 0; j < 2; ++j) acc[i][j] = (floatx4){0.f, 0.f, 0.f, 0.f};

  for (int k0 = 0; k0 < 1024; k0 += 32) {
    __syncthreads();
#pragma unroll
    for (int i = 0; i < 2; ++i) {
      int c   = i * 256 + tid;
      int row = c >> 2;
      int cs  = (c & 3) ^ ((c >> 3) & 3);
      async_copy16(A + (size_t)(m0 + row) * 1024 + k0 + cs * 8, sA + c * 8);
    }
    {
      int row = tid >> 2;
      int cs  = (tid & 3) ^ ((tid >> 3) & 3);
      async_copy16(W + (size_t)(n0 + row) * 1024 + k0 + cs * 8, sB + tid * 8);
    }
    __syncthreads();
    short8 af[4], bf[2];
#pragma unroll
    for (int mi = 0; mi < 4; ++mi)
      af[mi] = *(const short8*)(sA + (wm + mi * 16 + col) * 32 + swz8);
#pragma unroll
    for (int ni = 0; ni < 2; ++ni)
      bf[ni] = *(const short8*)(sB + (wn + ni * 16 + col) * 32 + swz8);
#pragma unroll
    for (int mi = 0; mi < 4; ++mi)
#pragma unroll
      for (int ni = 0; ni < 2; ++ni)
        acc[mi][ni] = __builtin_amdgcn_mfma_f32_16x16x32_bf16(af[mi], bf[ni], acc[mi][ni], 0, 0, 0);
  }

#pragma unroll
  for (int ni = 0; ni < 2; ++ni) {
    int n = n0 + wn + ni * 16 + col;
    float bv = bias[n];
#pragma unroll
    for (int mi = 0; mi < 4; ++mi) {
      int mbase = m0 + wm + mi * 16 + quad * 4;
#pragma unroll
      for (int r = 0; r < 4; ++r)
        DF[(size_t)(mbase + r) * 1024 + n] = acc[mi][ni][r] + bv;
    }
  }
}

// Flash attention (R7 structure + swizzled sQ/sK/sV): max-free softmax, Q
// pre-scaled so p=exp2(s). QK computed transposed (A=K,B=Q); packed b64
// P-writes, b128 P-reads (sP stride-72 already conflict-free).
__global__ __launch_bounds__(256, 4) void attention_kernel(
    const unsigned short* __restrict__ Q, const unsigned short* __restrict__ K,
    const unsigned short* __restrict__ VT, unsigned short* __restrict__ CTX)
{
  __shared__ alignas(16) unsigned short sQ[2 * 64 * 32];
  __shared__ alignas(16) unsigned short sK[2 * 64 * 32];
  __shared__ alignas(16) unsigned short sV[2 * 64 * 32];
  __shared__ alignas(16) unsigned short sP[4][16 * 72];  // [wave][q=16 rows x 72]

  const int bh = blockIdx.x;
  const int b = bh >> 4, h = bh & 15;
  const int q0 = blockIdx.y * 64;
  const int tid  = threadIdx.x;
  const int lane = tid & 63;
  const int wave = tid >> 6;
  const int col  = lane & 15;
  const int quad = lane >> 4;
  const int swz8 = (quad ^ ((col >> 1) & 3)) * 8;

  const int srow = tid >> 2;                      // staging row within slab
  const int sko  = ((tid & 3) ^ ((tid >> 3) & 3)) * 8;  // swizzled source chunk

#pragma unroll
  for (int i = 0; i < 2; ++i) {
    async_copy16(Q + (size_t)(b * 2048 + q0 + srow) * 1024 + h * 64 + i * 32 + sko,
                 sQ + (i * 256 + tid) * 8);
  }
  __syncthreads();
  short8 qf[2];
  qf[0] = *(const short8*)(sQ + (wave * 16 + col) * 32 + swz8);
  qf[1] = *(const short8*)(sQ + 2048 + (wave * 16 + col) * 32 + swz8);

  floatx4 Oacc[4];
#pragma unroll
  for (int f = 0; f < 4; ++f) Oacc[f] = (floatx4){0.f, 0.f, 0.f, 0.f};
  float lacc = 0.f;  // per-lane partial sum for q = col

  unsigned short* myP = &sP[wave][0];

  for (int kt = 0; kt < 2048; kt += 64) {
    __syncthreads();
#pragma unroll
    for (int i = 0; i < 2; ++i) {
      async_copy16(K + (size_t)(b * 2048 + kt + srow) * 1024 + h * 64 + i * 32 + sko,
                   sK + (i * 256 + tid) * 8);
      async_copy16(VT + ((size_t)bh * 64 + srow) * 2048 + kt + i * 32 + sko,
                   sV + (i * 256 + tid) * 8);
    }
    __syncthreads();

    // S^T blocks: rows k = f*16+quad*4+r, col q
    floatx4 ST[4];
#pragma unroll
    for (int f = 0; f < 4; ++f) {
      ST[f] = (floatx4){0.f, 0.f, 0.f, 0.f};
      short8 kf0 = *(const short8*)(sK + (f * 16 + col) * 32 + swz8);
      ST[f] = __builtin_amdgcn_mfma_f32_16x16x32_bf16(kf0, qf[0], ST[f], 0, 0, 0);
      short8 kf1 = *(const short8*)(sK + 2048 + (f * 16 + col) * 32 + swz8);
      ST[f] = __builtin_amdgcn_mfma_f32_16x16x32_bf16(kf1, qf[1], ST[f], 0, 0, 0);
    }

#pragma unroll
    for (int f = 0; f < 4; ++f) {
      float p0 = fast_exp2(ST[f][0]);
      float p1 = fast_exp2(ST[f][1]);
      float p2 = fast_exp2(ST[f][2]);
      float p3 = fast_exp2(ST[f][3]);
      lacc += (p0 + p1) + (p2 + p3);
      unsigned long long w =
          ((unsigned long long)f2b_pk(p2, p3) << 32) | f2b_pk(p0, p1);
      *(unsigned long long*)(myP + col * 72 + f * 16 + quad * 4) = w;
    }

    // wave-private sP: lgkmcnt orders write->read, no barrier needed.
    short8 pf0 = *(const short8*)(myP + col * 72 + quad * 8);
    short8 pf1 = *(const short8*)(myP + col * 72 + 32 + quad * 8);
#pragma unroll
    for (int f = 0; f < 4; ++f) {
      short8 vf0 = *(const short8*)(sV + (f * 16 + col) * 32 + swz8);
      Oacc[f] = __builtin_amdgcn_mfma_f32_16x16x32_bf16(pf0, vf0, Oacc[f], 0, 0, 0);
      short8 vf1 = *(const short8*)(sV + 2048 + (f * 16 + col) * 32 + swz8);
      Oacc[f] = __builtin_amdgcn_mfma_f32_16x16x32_bf16(pf1, vf1, Oacc[f], 0, 0, 0);
    }
  }

  // lacc holds partial sum for q=col over this quad's k slices; sum quads.
  lacc += __shfl_xor(lacc, 16, 64);
  lacc += __shfl_xor(lacc, 32, 64);
  // row sums for this lane's output rows q = quad*4+r
  float inv[4];
#pragma unroll
  for (int r = 0; r < 4; ++r) inv[r] = 1.f / __shfl(lacc, quad * 4 + r, 16);

#pragma unroll
  for (int f = 0; f < 4; ++f) {
#pragma unroll
    for (int r = 0; r < 4; ++r) {
      int q = q0 + wave * 16 + quad * 4 + r;
      int d = f * 16 + col;
      CTX[(size_t)(b * 2048 + q) * 1024 + h * 64 + d] = f2b(Oacc[f][r] * inv[r]);
    }
  }
}

extern "C" void kernel_launch(void* const* d_in, const int* in_sizes, int n_in,
                              void* d_out, int out_size, void* d_ws, size_t ws_size,
                              hipStream_t stream) {
  const float* x   = (const float*)d_in[0];
  const float* W_q = (const float*)d_in[1];
  const float* b_q = (const float*)d_in[2];
  const float* W_k = (const float*)d_in[3];
  const float* b_k = (const float*)d_in[4];
  const float* W_v = (const float*)d_in[5];
  const float* b_v = (const float*)d_in[6];
  const float* W_o = (const float*)d_in[7];
  const float* b_o = (const float*)d_in[8];
  float* out = (float*)d_out;

  const size_t NX = (size_t)4096 * 1024;
  const size_t NW = (size_t)1024 * 1024;

  unsigned short* p   = (unsigned short*)d_ws;
  unsigned short* xb  = p;  p += NX;
  unsigned short* Wqb = p;  p += NW;
  unsigned short* Wkb = p;  p += NW;
  unsigned short* Wvb = p;  p += NW;
  unsigned short* Wob = p;  p += NW;
  unsigned short* Q   = p;  p += NX;
  unsigned short* Kb  = p;  p += NX;
  unsigned short* VT  = p;  p += NX;  // [32][64][2048]
  unsigned short* CTX = p;  p += NX;

  dim3 blk(256);
  cvt_all_kernel<<<dim3(8192), blk, 0, stream>>>(
      x, W_q, W_k, W_v, W_o, xb, Wqb, Wkb, Wvb, Wob);
  gemm_qkv_kernel<<<dim3(8, 32, 3), blk, 0, stream>>>(
      xb, Wqb, Wkb, Wvb, b_q, b_k, b_v, Q, Kb, VT);
  attention_kernel<<<dim3(32, 32), blk, 0, stream>>>(Q, Kb, VT, CTX);
  gemm_out_kernel<<<dim3(16, 32), blk, 0, stream>>>(CTX, Wob, b_o, out);
}